// Round 14
// baseline (5950.650 us; speedup 1.0000x reference)
//
#include <hip/hip_runtime.h>
#include <hip/hip_bf16.h>
#include <math.h>

#define NC_DIM 8192
#define C_DIM 2048
#define NTOK 8192
#define EPS_RMS 1.1920929e-07f

typedef __bf16 bf16_t;
typedef __attribute__((ext_vector_type(8))) __bf16 bf16x8;
typedef __attribute__((ext_vector_type(4))) __bf16 bf16x4;
typedef __attribute__((ext_vector_type(4))) float f32x4;

__device__ __forceinline__ void gload_lds16(const void* g, void* l) {
    __builtin_amdgcn_global_load_lds(
        (const __attribute__((address_space(1))) void*)g,
        (__attribute__((address_space(3))) void*)l, 16, 0, 0);
}

// 2D-chunked XCD swizzle (bijective for grid=1024 and grid=256)
__device__ __forceinline__ void tile_swz(int bid, long& tm, long& tn) {
    const int x8 = bid & 7;
    const int l = bid >> 3;
    tm = (long)(x8 * 4 + ((l >> 3) & 3)) * 256;
    tn = (long)((l >> 5) * 8 + (l & 7)) * 256;
}

// ---------------- fp32 -> bf16 conversion (W1, W2) ----------------
__global__ __launch_bounds__(256) void cvt_f32_bf16(const float* __restrict__ in,
                                                    bf16_t* __restrict__ out,
                                                    const int n4) {
    int i = blockIdx.x * 256 + threadIdx.x;
    const int stride = gridDim.x * 256;
    for (; i < n4; i += stride) {
        f32x4 v = ((const f32x4*)in)[i];
        bf16x4 bv;
        bv.x = (__bf16)v.x; bv.y = (__bf16)v.y; bv.z = (__bf16)v.z; bv.w = (__bf16)v.w;
        ((bf16x4*)out)[i] = bv;
    }
}

// ---------------- projection + per-token scalars + FUSED layer-input mix ---
__global__ __launch_bounds__(256) void k_proj(
    const float* __restrict__ x,      // [NTOK][8192]
    const float* __restrict__ Wall,   // [32][8192]
    const float* __restrict__ ball,   // [32]
    const float* __restrict__ apre,
    const float* __restrict__ apost,
    const float* __restrict__ ares,
    const float* __restrict__ perm,   // [24][16]
    float* __restrict__ hpost_g,      // [NTOK][4]
    float* __restrict__ Hm_g,         // [NTOK][16]
    bf16_t* __restrict__ li)          // [NTOK][2048]
{
    __shared__ __align__(16) bf16_t xs[32 * 264];
    __shared__ __align__(16) bf16_t wsl[32 * 264];
    __shared__ float dparts[4][32][32];
    __shared__ float ssq_s[32];
    __shared__ float Ps[384];
    __shared__ float hps[32][4];

    const int t = threadIdx.x;
    const int lane = t & 63;
    const int w = t >> 6;
    const int tok0 = blockIdx.x * 32;

    for (int i = t; i < 384; i += 256) Ps[i] = perm[i];

    const int row = t >> 3;
    const int i8 = t & 7;

    const float* xrow = x + (size_t)(tok0 + row) * (size_t)NC_DIM;
    const float* wrow = Wall + (size_t)row * (size_t)NC_DIM;

    float ssq = 0.0f;
    f32x4 acc[2][2];
#pragma unroll
    for (int m = 0; m < 2; ++m)
#pragma unroll
        for (int n = 0; n < 2; ++n) acc[m][n] = (f32x4){0.f, 0.f, 0.f, 0.f};

    const int rsel = lane & 15;
    const int ko_base = (lane >> 4) * 8;

    for (int kt = 0; kt < NC_DIM; kt += 256) {
        __syncthreads();
#pragma unroll
        for (int q = 0; q < 8; ++q) {
            const int col = (i8 + q * 8) * 4;
            f32x4 v = *(const f32x4*)(xrow + kt + col);
            ssq += v.x * v.x + v.y * v.y + v.z * v.z + v.w * v.w;
            bf16x4 bv;
            bv.x = (__bf16)v.x; bv.y = (__bf16)v.y; bv.z = (__bf16)v.z; bv.w = (__bf16)v.w;
            *(bf16x4*)(xs + row * 264 + col) = bv;
            f32x4 u = *(const f32x4*)(wrow + kt + col);
            bf16x4 bu;
            bu.x = (__bf16)u.x; bu.y = (__bf16)u.y; bu.z = (__bf16)u.z; bu.w = (__bf16)u.w;
            *(bf16x4*)(wsl + row * 264 + col) = bu;
        }
        __syncthreads();
#pragma unroll
        for (int ks = 0; ks < 2; ++ks) {
            const int ko = w * 64 + ks * 32 + ko_base;
            bf16x8 a0 = *(const bf16x8*)(xs + rsel * 264 + ko);
            bf16x8 a1 = *(const bf16x8*)(xs + (16 + rsel) * 264 + ko);
            bf16x8 b0 = *(const bf16x8*)(wsl + rsel * 264 + ko);
            bf16x8 b1 = *(const bf16x8*)(wsl + (16 + rsel) * 264 + ko);
            acc[0][0] = __builtin_amdgcn_mfma_f32_16x16x32_bf16(a0, b0, acc[0][0], 0, 0, 0);
            acc[0][1] = __builtin_amdgcn_mfma_f32_16x16x32_bf16(a0, b1, acc[0][1], 0, 0, 0);
            acc[1][0] = __builtin_amdgcn_mfma_f32_16x16x32_bf16(a1, b0, acc[1][0], 0, 0, 0);
            acc[1][1] = __builtin_amdgcn_mfma_f32_16x16x32_bf16(a1, b1, acc[1][1], 0, 0, 0);
        }
    }

    ssq += __shfl_xor(ssq, 1);
    ssq += __shfl_xor(ssq, 2);
    ssq += __shfl_xor(ssq, 4);
    if (i8 == 0) ssq_s[row] = ssq;

    const int cr = (lane >> 4) * 4;
#pragma unroll
    for (int m = 0; m < 2; ++m)
#pragma unroll
        for (int n = 0; n < 2; ++n)
#pragma unroll
            for (int j = 0; j < 4; ++j)
                dparts[w][m * 16 + cr + j][n * 16 + rsel] = acc[m][n][j];
    __syncthreads();

    if (t < 32) {
        const int g = tok0 + t;
        const float rinv = rsqrtf(ssq_s[t] * (1.0f / (float)NC_DIM) + EPS_RMS);
        float proj[32];
#pragma unroll
        for (int r = 0; r < 32; ++r)
            proj[r] = (dparts[0][t][r] + dparts[1][t][r] + dparts[2][t][r] + dparts[3][t][r]) * rinv;
        const float aP = apre[0], aQ = apost[0], aR = ares[0];
        float hp[4], hq[4];
#pragma unroll
        for (int i = 0; i < 4; ++i) {
            hp[i] = 1.0f / (1.0f + expf(-(aP * proj[i] + __ldg(&ball[i]))));
            hq[i] = 2.0f / (1.0f + expf(-(aQ * proj[4 + i] + __ldg(&ball[4 + i]))));
            hps[t][i] = hp[i];
        }
        float zb[24];
        float mx = -1e30f;
#pragma unroll
        for (int p = 0; p < 24; ++p) {
            zb[p] = aR * proj[8 + p] + __ldg(&ball[8 + p]);
            mx = fmaxf(mx, zb[p]);
        }
        float s = 0.f;
#pragma unroll
        for (int p = 0; p < 24; ++p) { zb[p] = expf(zb[p] - mx); s += zb[p]; }
        const float is = 1.0f / s;
        float Hr[16];
#pragma unroll
        for (int idx = 0; idx < 16; ++idx) Hr[idx] = 0.f;
#pragma unroll
        for (int p = 0; p < 24; ++p) {
            const float a = zb[p] * is;
#pragma unroll
            for (int idx = 0; idx < 16; ++idx) Hr[idx] += a * Ps[p * 16 + idx];
        }
#pragma unroll
        for (int i = 0; i < 4; ++i) {
            hpost_g[(size_t)g * 4 + i] = hq[i];
#pragma unroll
            for (int j = 0; j < 4; ++j)
                Hm_g[(size_t)g * 16 + i * 4 + j] = Hr[i * 4 + j] - hq[i] * hp[j];
        }
    }
    __syncthreads();

    // ---- fused k_mix ----
    const float h0 = hps[row][0], h1 = hps[row][1], h2 = hps[row][2], h3 = hps[row][3];
    bf16_t* lo = li + (size_t)(tok0 + row) * (size_t)C_DIM;
#pragma unroll 4
    for (int q = 0; q < 64; ++q) {
        const int c = (i8 + q * 8) * 4;
        f32x4 v0 = *(const f32x4*)(xrow + c);
        f32x4 v1 = *(const f32x4*)(xrow + 2048 + c);
        f32x4 v2 = *(const f32x4*)(xrow + 4096 + c);
        f32x4 v3 = *(const f32x4*)(xrow + 6144 + c);
        f32x4 r = h0 * v0 + h1 * v1 + h2 * v2 + h3 * v3;
        bf16x4 bv;
        bv.x = (__bf16)r.x; bv.y = (__bf16)r.y; bv.z = (__bf16)r.z; bv.w = (__bf16)r.w;
        *(bf16x4*)(lo + c) = bv;
    }
}

// ============ 256x256 tile, BK=32, 64KB LDS -> 2 blocks/CU (NEW AXIS) ======
// All prior 256^2 variants ran 1 block/CU (2 waves/SIMD): every barrier/wait
// bubble was unfillable. BK=32 halves LDS to 2x32KB -> 2 blocks/CU ->
// 4 waves/SIMD; co-resident block fills the other's stalls (m114 mechanism).
// Per K-tile: {12 ds_reads -> 32 MFMA -> barrier -> stage(t+2)->s -> vmcnt(4)
// -> barrier}. WAR: stage after all-waves-read barrier. Visibility: vmcnt(4)
// at iter t drains tile t+1's 4 loads (issued >=1 full tile earlier).
// Core is a device-inline function (R13's macro form tripped "#pragma in
// macro argument"); __shared__ inside a device function is block-scoped.

__device__ __forceinline__ void gemm_core_bk32(
    const bf16_t* __restrict__ A, const bf16_t* __restrict__ Bm, const int K,
    f32x4 (&acc)[8][4], long& tm, long& tn,
    int& wr_o, int& wc_o, int& rsel_o, int& lane_o)
{
    __shared__ __align__(16) char lds[65536];
    const int tid = threadIdx.x;
    const int lane = tid & 63;
    const int w = tid >> 6;
    const int wr = w >> 2;
    const int wc = w & 3;
    tile_swz(blockIdx.x, tm, tn);
    const int NT = K >> 5;
    const int rsel = lane & 15;
    const int ko = (lane >> 4) * 8;
    const int lane_off = rsel * 64 + ((ko ^ (((rsel >> 1) & 3) << 3)) << 1);
    const char* Abytes = (const char*)A;
    const char* Bbytes = (const char*)Bm;
    size_t asrc[2], bsrc[2];
#pragma unroll
    for (int i = 0; i < 2; ++i) {
        const int d = i * 8192 + tid * 16;
        const int sub = d >> 10;
        const int rr = (d >> 6) & 15;
        const int kk = ((d & 63) >> 1) ^ (((rr >> 1) & 3) << 3);
        asrc[i] = ((size_t)(tm + sub * 16 + rr) * K + kk) * 2;
        bsrc[i] = ((size_t)(tn + sub * 16 + rr) * K + kk) * 2;
    }
    auto stage = [&](int tile, int slot) {
        const int tt = tile < NT ? tile : NT - 1;
        const size_t koff = (size_t)tt * 64;
        char* base = lds + slot * 32768 + tid * 16;
        gload_lds16(Abytes + asrc[0] + koff, base);
        gload_lds16(Abytes + asrc[1] + koff, base + 8192);
        gload_lds16(Bbytes + bsrc[0] + koff, base + 16384);
        gload_lds16(Bbytes + bsrc[1] + koff, base + 24576);
    };
#pragma unroll
    for (int m = 0; m < 8; ++m)
#pragma unroll
        for (int n = 0; n < 4; ++n) acc[m][n] = (f32x4){0.f, 0.f, 0.f, 0.f};
    bf16x8 aR[8], bR[4];
    stage(0, 0);
    stage(1, 1);
    asm volatile("s_waitcnt vmcnt(4)" ::: "memory");
    __builtin_amdgcn_s_barrier();
    for (int t = 0; t < NT; ++t) {
        const int s = t & 1;
        const char* aS = lds + s * 32768 + (wr * 8) * 1024;
        const char* bS = lds + s * 32768 + 16384 + (wc * 4) * 1024;
#pragma unroll
        for (int nf = 0; nf < 4; ++nf)
            bR[nf] = *(const bf16x8*)(bS + nf * 1024 + lane_off);
#pragma unroll
        for (int mf = 0; mf < 8; ++mf)
            aR[mf] = *(const bf16x8*)(aS + mf * 1024 + lane_off);
        __builtin_amdgcn_s_setprio(1);
#pragma unroll
        for (int mf = 0; mf < 8; ++mf)
#pragma unroll
            for (int nf = 0; nf < 4; ++nf)
                acc[mf][nf] = __builtin_amdgcn_mfma_f32_16x16x32_bf16(
                    aR[mf], bR[nf], acc[mf][nf], 0, 0, 0);
        __builtin_amdgcn_s_setprio(0);
        __builtin_amdgcn_s_barrier();
        stage(t + 2, s);
        asm volatile("s_waitcnt vmcnt(4)" ::: "memory");
        __builtin_amdgcn_s_barrier();
    }
    wr_o = wr; wc_o = wc; rsel_o = rsel; lane_o = lane;
}

__global__ __launch_bounds__(512, 4) void gemm1k(
    const bf16_t* __restrict__ A,   // li [M][K]
    const bf16_t* __restrict__ Bm,  // W1 [N][K]
    const float* __restrict__ bias, // b1
    bf16_t* __restrict__ Cout,      // h [M][N]
    const int M, const int N, const int K)
{
    f32x4 acc[8][4];
    long tm, tn;
    int wr, wc, rsel, lane;
    gemm_core_bk32(A, Bm, K, acc, tm, tn, wr, wc, rsel, lane);

#pragma unroll
    for (int mf = 0; mf < 8; ++mf) {
        const long rbase = tm + wr * 128 + mf * 16 + (lane >> 4) * 4;
#pragma unroll
        for (int nf = 0; nf < 4; ++nf) {
            const long cg = tn + wc * 64 + nf * 16 + rsel;
            const float bv = __ldg(&bias[cg]);
            const f32x4 v4 = acc[mf][nf];
#pragma unroll
            for (int j = 0; j < 4; ++j) {
                const float v = v4[j] + bv;
                const float ge = 0.5f * v * (1.0f + erff(v * 0.70710678118654752f));
                Cout[(size_t)(rbase + j) * N + cg] = (__bf16)ge;
            }
        }
    }
}

__global__ __launch_bounds__(512, 4) void gemm2f(
    const bf16_t* __restrict__ A,   // h [M][K]
    const bf16_t* __restrict__ Bm,  // W2 [N][K]
    const float* __restrict__ bias, // b2
    float* __restrict__ outp,       // [M][4][2048]
    const int M, const int N, const int K,
    const float* __restrict__ xg,
    const float* __restrict__ hpost_g,
    const float* __restrict__ Hm_g)
{
    f32x4 acc[8][4];
    long tm, tn;
    int wr, wc, rsel, lane;
    gemm_core_bk32(A, Bm, K, acc, tm, tn, wr, wc, rsel, lane);

#pragma unroll
    for (int mf = 0; mf < 8; ++mf) {
        const long rbase = tm + wr * 128 + mf * 16 + (lane >> 4) * 4;
#pragma unroll
        for (int j = 0; j < 4; ++j) {
            const long tok = rbase + j;
            float H[16], hq[4];
#pragma unroll
            for (int z = 0; z < 16; ++z) H[z] = __ldg(&Hm_g[tok * 16 + z]);
#pragma unroll
            for (int z = 0; z < 4; ++z) hq[z] = __ldg(&hpost_g[tok * 4 + z]);
            const float* xrow = xg + (size_t)tok * (size_t)NC_DIM;
            float* orow = outp + (size_t)tok * (size_t)NC_DIM;
#pragma unroll
            for (int nf = 0; nf < 4; ++nf) {
                const long cg = tn + wc * 64 + nf * 16 + rsel;
                const float lo = acc[mf][nf][j] + __ldg(&bias[cg]);
                const float x0 = xrow[cg];
                const float x1 = xrow[2048 + cg];
                const float x2 = xrow[4096 + cg];
                const float x3 = xrow[6144 + cg];
#pragma unroll
                for (int i = 0; i < 4; ++i)
                    orow[i * 2048 + cg] =
                        H[i * 4 + 0] * x0 + H[i * 4 + 1] * x1 +
                        H[i * 4 + 2] * x2 + H[i * 4 + 3] * x3 + hq[i] * lo;
            }
        }
    }
}

extern "C" void kernel_launch(void* const* d_in, const int* in_sizes, int n_in,
                              void* d_out, int out_size, void* d_ws, size_t ws_size,
                              hipStream_t stream) {
    const float* x     = (const float*)d_in[0];
    const float* Wall  = (const float*)d_in[1];
    const float* ball  = (const float*)d_in[2];
    const float* apre  = (const float*)d_in[3];
    const float* apost = (const float*)d_in[4];
    const float* ares  = (const float*)d_in[5];
    const float* W1    = (const float*)d_in[6];
    const float* b1    = (const float*)d_in[7];
    const float* W2    = (const float*)d_in[8];
    const float* b2    = (const float*)d_in[9];
    const float* perm  = (const float*)d_in[10];
    float* out = (float*)d_out;
    char* ws = (char*)d_ws;

    // workspace layout (bytes)
    bf16_t* W1b  = (bf16_t*)(ws);                  //  32 MB  [8192][2048]
    bf16_t* W2b  = (bf16_t*)(ws + 33554432ull);    //  32 MB  [2048][8192]
    bf16_t* li   = (bf16_t*)(ws + 67108864ull);    //  32 MB  [8192][2048]
    bf16_t* h    = (bf16_t*)(ws + 100663296ull);   // 128 MB  [8192][8192]
    float*  hpost= (float*)(ws + 302120960ull);    // 128 KB  [8192][4]
    float*  Hm   = (float*)(ws + 302252032ull);    // 512 KB  [8192][16]

    cvt_f32_bf16<<<2048, 256, 0, stream>>>(W1, W1b, 16777216 / 4);
    cvt_f32_bf16<<<2048, 256, 0, stream>>>(W2, W2b, 16777216 / 4);
    k_proj<<<256, 256, 0, stream>>>(x, Wall, ball, apre, apost, ares, perm, hpost, Hm, li);
    gemm1k<<<1024, 512, 0, stream>>>(li, W1b, b1, h, 8192, 8192, 2048);
    gemm2f<<<256, 512, 0, stream>>>(h, W2b, b2, out, 8192, 2048, 8192,
                                    x, hpost, Hm);
}

// Round 15
// 784.528 us; speedup vs baseline: 7.5850x; 7.5850x over previous
//
#include <hip/hip_runtime.h>
#include <hip/hip_bf16.h>
#include <math.h>

#define NC_DIM 8192
#define C_DIM 2048
#define NTOK 8192
#define EPS_RMS 1.1920929e-07f

typedef __bf16 bf16_t;
typedef __attribute__((ext_vector_type(8))) __bf16 bf16x8;
typedef __attribute__((ext_vector_type(4))) __bf16 bf16x4;
typedef __attribute__((ext_vector_type(4))) float f32x4;

__device__ __forceinline__ void gload_lds16(const void* g, void* l) {
    __builtin_amdgcn_global_load_lds(
        (const __attribute__((address_space(1))) void*)g,
        (__attribute__((address_space(3))) void*)l, 16, 0, 0);
}

// 2D-chunked XCD swizzle (bijective for grid=1024 and grid=256)
__device__ __forceinline__ void tile_swz(int bid, long& tm, long& tn) {
    const int x8 = bid & 7;
    const int l = bid >> 3;
    tm = (long)(x8 * 4 + ((l >> 3) & 3)) * 256;
    tn = (long)((l >> 5) * 8 + (l & 7)) * 256;
}

// ---------------- fp32 -> bf16 conversion (W1 and W2 in one launch) -------
__global__ __launch_bounds__(256) void cvt_both(const float* __restrict__ w1,
                                                const float* __restrict__ w2,
                                                bf16_t* __restrict__ o1,
                                                bf16_t* __restrict__ o2,
                                                const int n4each) {
    int i = blockIdx.x * 256 + threadIdx.x;
    const int stride = gridDim.x * 256;
    for (; i < n4each; i += stride) {
        f32x4 v = ((const f32x4*)w1)[i];
        bf16x4 bv;
        bv.x = (__bf16)v.x; bv.y = (__bf16)v.y; bv.z = (__bf16)v.z; bv.w = (__bf16)v.w;
        ((bf16x4*)o1)[i] = bv;
        f32x4 u = ((const f32x4*)w2)[i];
        bf16x4 bu;
        bu.x = (__bf16)u.x; bu.y = (__bf16)u.y; bu.z = (__bf16)u.z; bu.w = (__bf16)u.w;
        ((bf16x4*)o2)[i] = bu;
    }
}

// ---------------- projection + per-token scalars + FUSED layer-input mix ---
__global__ __launch_bounds__(256) void k_proj(
    const float* __restrict__ x,      // [NTOK][8192]
    const float* __restrict__ Wall,   // [32][8192]
    const float* __restrict__ ball,   // [32]
    const float* __restrict__ apre,
    const float* __restrict__ apost,
    const float* __restrict__ ares,
    const float* __restrict__ perm,   // [24][16]
    float* __restrict__ hpost_g,      // [NTOK][4]
    float* __restrict__ Hm_g,         // [NTOK][16]
    bf16_t* __restrict__ li)          // [NTOK][2048]
{
    __shared__ __align__(16) bf16_t xs[32 * 264];
    __shared__ __align__(16) bf16_t wsl[32 * 264];
    __shared__ float dparts[4][32][32];
    __shared__ float ssq_s[32];
    __shared__ float Ps[384];
    __shared__ float hps[32][4];

    const int t = threadIdx.x;
    const int lane = t & 63;
    const int w = t >> 6;
    const int tok0 = blockIdx.x * 32;

    for (int i = t; i < 384; i += 256) Ps[i] = perm[i];

    const int row = t >> 3;
    const int i8 = t & 7;

    const float* xrow = x + (size_t)(tok0 + row) * (size_t)NC_DIM;
    const float* wrow = Wall + (size_t)row * (size_t)NC_DIM;

    float ssq = 0.0f;
    f32x4 acc[2][2];
#pragma unroll
    for (int m = 0; m < 2; ++m)
#pragma unroll
        for (int n = 0; n < 2; ++n) acc[m][n] = (f32x4){0.f, 0.f, 0.f, 0.f};

    const int rsel = lane & 15;
    const int ko_base = (lane >> 4) * 8;

    for (int kt = 0; kt < NC_DIM; kt += 256) {
        __syncthreads();
#pragma unroll
        for (int q = 0; q < 8; ++q) {
            const int col = (i8 + q * 8) * 4;
            f32x4 v = *(const f32x4*)(xrow + kt + col);
            ssq += v.x * v.x + v.y * v.y + v.z * v.z + v.w * v.w;
            bf16x4 bv;
            bv.x = (__bf16)v.x; bv.y = (__bf16)v.y; bv.z = (__bf16)v.z; bv.w = (__bf16)v.w;
            *(bf16x4*)(xs + row * 264 + col) = bv;
            f32x4 u = *(const f32x4*)(wrow + kt + col);
            bf16x4 bu;
            bu.x = (__bf16)u.x; bu.y = (__bf16)u.y; bu.z = (__bf16)u.z; bu.w = (__bf16)u.w;
            *(bf16x4*)(wsl + row * 264 + col) = bu;
        }
        __syncthreads();
#pragma unroll
        for (int ks = 0; ks < 2; ++ks) {
            const int ko = w * 64 + ks * 32 + ko_base;
            bf16x8 a0 = *(const bf16x8*)(xs + rsel * 264 + ko);
            bf16x8 a1 = *(const bf16x8*)(xs + (16 + rsel) * 264 + ko);
            bf16x8 b0 = *(const bf16x8*)(wsl + rsel * 264 + ko);
            bf16x8 b1 = *(const bf16x8*)(wsl + (16 + rsel) * 264 + ko);
            acc[0][0] = __builtin_amdgcn_mfma_f32_16x16x32_bf16(a0, b0, acc[0][0], 0, 0, 0);
            acc[0][1] = __builtin_amdgcn_mfma_f32_16x16x32_bf16(a0, b1, acc[0][1], 0, 0, 0);
            acc[1][0] = __builtin_amdgcn_mfma_f32_16x16x32_bf16(a1, b0, acc[1][0], 0, 0, 0);
            acc[1][1] = __builtin_amdgcn_mfma_f32_16x16x32_bf16(a1, b1, acc[1][1], 0, 0, 0);
        }
    }

    ssq += __shfl_xor(ssq, 1);
    ssq += __shfl_xor(ssq, 2);
    ssq += __shfl_xor(ssq, 4);
    if (i8 == 0) ssq_s[row] = ssq;

    const int cr = (lane >> 4) * 4;
#pragma unroll
    for (int m = 0; m < 2; ++m)
#pragma unroll
        for (int n = 0; n < 2; ++n)
#pragma unroll
            for (int j = 0; j < 4; ++j)
                dparts[w][m * 16 + cr + j][n * 16 + rsel] = acc[m][n][j];
    __syncthreads();

    if (t < 32) {
        const int g = tok0 + t;
        const float rinv = rsqrtf(ssq_s[t] * (1.0f / (float)NC_DIM) + EPS_RMS);
        float proj[32];
#pragma unroll
        for (int r = 0; r < 32; ++r)
            proj[r] = (dparts[0][t][r] + dparts[1][t][r] + dparts[2][t][r] + dparts[3][t][r]) * rinv;
        const float aP = apre[0], aQ = apost[0], aR = ares[0];
        float hp[4], hq[4];
#pragma unroll
        for (int i = 0; i < 4; ++i) {
            hp[i] = 1.0f / (1.0f + expf(-(aP * proj[i] + __ldg(&ball[i]))));
            hq[i] = 2.0f / (1.0f + expf(-(aQ * proj[4 + i] + __ldg(&ball[4 + i]))));
            hps[t][i] = hp[i];
        }
        float zb[24];
        float mx = -1e30f;
#pragma unroll
        for (int p = 0; p < 24; ++p) {
            zb[p] = aR * proj[8 + p] + __ldg(&ball[8 + p]);
            mx = fmaxf(mx, zb[p]);
        }
        float s = 0.f;
#pragma unroll
        for (int p = 0; p < 24; ++p) { zb[p] = expf(zb[p] - mx); s += zb[p]; }
        const float is = 1.0f / s;
        float Hr[16];
#pragma unroll
        for (int idx = 0; idx < 16; ++idx) Hr[idx] = 0.f;
#pragma unroll
        for (int p = 0; p < 24; ++p) {
            const float a = zb[p] * is;
#pragma unroll
            for (int idx = 0; idx < 16; ++idx) Hr[idx] += a * Ps[p * 16 + idx];
        }
#pragma unroll
        for (int i = 0; i < 4; ++i) {
            hpost_g[(size_t)g * 4 + i] = hq[i];
#pragma unroll
            for (int j = 0; j < 4; ++j)
                Hm_g[(size_t)g * 16 + i * 4 + j] = Hr[i * 4 + j] - hq[i] * hp[j];
        }
    }
    __syncthreads();

    // ---- fused k_mix ----
    const float h0 = hps[row][0], h1 = hps[row][1], h2 = hps[row][2], h3 = hps[row][3];
    bf16_t* lo = li + (size_t)(tok0 + row) * (size_t)C_DIM;
#pragma unroll 4
    for (int q = 0; q < 64; ++q) {
        const int c = (i8 + q * 8) * 4;
        f32x4 v0 = *(const f32x4*)(xrow + c);
        f32x4 v1 = *(const f32x4*)(xrow + 2048 + c);
        f32x4 v2 = *(const f32x4*)(xrow + 4096 + c);
        f32x4 v3 = *(const f32x4*)(xrow + 6144 + c);
        f32x4 r = h0 * v0 + h1 * v1 + h2 * v2 + h3 * v3;
        bf16x4 bv;
        bv.x = (__bf16)r.x; bv.y = (__bf16)r.y; bv.z = (__bf16)r.z; bv.w = (__bf16)r.w;
        *(bf16x4*)(lo + c) = bv;
    }
}

// ---------------- GEMM core (R4/R12 best: 256^2, BK=64, 1 barrier/phase,
// counted vmcnt(6), conflict-free swizzle, 2D-chunked XCD swizzle) ---------

__global__ __launch_bounds__(512, 2) void gemm1k(
    const bf16_t* __restrict__ A,   // li [M][K]
    const bf16_t* __restrict__ Bm,  // W1 [N][K]
    const float* __restrict__ bias, // b1
    bf16_t* __restrict__ Cout,      // h [M][N]
    const int M, const int N, const int K)
{
    __shared__ __align__(16) char lds[131072];
    const int tid = threadIdx.x;
    const int lane = tid & 63;
    const int w = tid >> 6;
    const int wr = w >> 2;
    const int wc = w & 3;

    long tm, tn;
    tile_swz(blockIdx.x, tm, tn);

    const int NT = K >> 6;

    const int rsel = lane & 15;
    const int ko = (lane >> 4) * 8;
    const int lane_off = rsel * 64 + ((ko ^ (((rsel >> 1) & 3) << 3)) << 1);

    const char* Abytes = (const char*)A;
    const char* Bbytes = (const char*)Bm;
    size_t asrc[2][2], bsrc[2][2];
#pragma unroll
    for (int i = 0; i < 2; ++i) {
        const int d = i * 8192 + tid * 16;
        {
            const int awr = d >> 13, rem = d & 8191;
            const int sub = rem >> 10, rs = sub >> 1, ksub = sub & 1;
            const int rr = (rem >> 6) & 15;
            const int kk = ((rem & 63) >> 1) ^ (((rr >> 1) & 3) << 3);
            const int k = ksub * 32 + kk;
#pragma unroll
            for (int mq = 0; mq < 2; ++mq) {
                const long grow = tm + awr * 128 + mq * 64 + rs * 16 + rr;
                asrc[mq][i] = ((size_t)grow * K + k) * 2;
            }
        }
        {
            const int bwc = d >> 12, rem = d & 4095;
            const int sub = rem >> 10, rs = sub >> 1, ksub = sub & 1;
            const int rr = (rem >> 6) & 15;
            const int kk = ((rem & 63) >> 1) ^ (((rr >> 1) & 3) << 3);
            const int k = ksub * 32 + kk;
#pragma unroll
            for (int np = 0; np < 2; ++np) {
                const long grow = tn + bwc * 64 + np * 32 + rs * 16 + rr;
                bsrc[np][i] = ((size_t)grow * K + k) * 2;
            }
        }
    }

    auto stageA = [&](int mq, int tile, int slot) {
        const int tt = tile < NT ? tile : NT - 1;
        char* dst = lds + slot * 65536 + mq * 16384 + w * 1024;
        gload_lds16(Abytes + asrc[mq][0] + (size_t)tt * 128, dst);
        gload_lds16(Abytes + asrc[mq][1] + (size_t)tt * 128, dst + 8192);
    };
    auto stageB = [&](int np, int tile, int slot) {
        const int tt = tile < NT ? tile : NT - 1;
        char* dst = lds + slot * 65536 + 32768 + np * 16384 + w * 1024;
        gload_lds16(Bbytes + bsrc[np][0] + (size_t)tt * 128, dst);
        gload_lds16(Bbytes + bsrc[np][1] + (size_t)tt * 128, dst + 8192);
    };

    const char* aB = lds + wr * 8192;
    const char* bB = lds + 32768 + wc * 4096;

    f32x4 acc[8][4];
#pragma unroll
    for (int m = 0; m < 8; ++m)
#pragma unroll
        for (int n = 0; n < 4; ++n) acc[m][n] = (f32x4){0.f, 0.f, 0.f, 0.f};

    bf16x8 aR[4][2], b01[2][2], b23[2][2];

    stageA(0, 0, 0); stageB(0, 0, 0); stageB(1, 0, 0); stageA(1, 0, 0);
    stageA(0, 1, 1); stageB(0, 1, 1); stageB(1, 1, 1);
    asm volatile("s_waitcnt vmcnt(6)" ::: "memory");
    __builtin_amdgcn_s_barrier();

    for (int t = 0; t < NT; ++t) {
        const int s = t & 1;
        const char* aS = aB + s * 65536;
        const char* bS = bB + s * 65536;
#pragma unroll
        for (int mf = 0; mf < 4; ++mf)
#pragma unroll
            for (int ks = 0; ks < 2; ++ks)
                aR[mf][ks] = *(const bf16x8*)(aS + (mf * 2 + ks) * 1024 + lane_off);
#pragma unroll
        for (int nf = 0; nf < 2; ++nf)
#pragma unroll
            for (int ks = 0; ks < 2; ++ks)
                b01[nf][ks] = *(const bf16x8*)(bS + (nf * 2 + ks) * 1024 + lane_off);
        stageA(1, t + 1, s ^ 1);
        __builtin_amdgcn_s_setprio(1);
#pragma unroll
        for (int mf = 0; mf < 4; ++mf)
#pragma unroll
            for (int nf = 0; nf < 2; ++nf)
#pragma unroll
                for (int ks = 0; ks < 2; ++ks)
                    acc[mf][nf] = __builtin_amdgcn_mfma_f32_16x16x32_bf16(aR[mf][ks], b01[nf][ks], acc[mf][nf], 0, 0, 0);
        __builtin_amdgcn_s_setprio(0);
        __builtin_amdgcn_s_barrier();
#pragma unroll
        for (int nf = 0; nf < 2; ++nf)
#pragma unroll
            for (int ks = 0; ks < 2; ++ks)
                b23[nf][ks] = *(const bf16x8*)(bS + 16384 + (nf * 2 + ks) * 1024 + lane_off);
        stageA(0, t + 2, s);
        __builtin_amdgcn_s_setprio(1);
#pragma unroll
        for (int mf = 0; mf < 4; ++mf)
#pragma unroll
            for (int nf = 0; nf < 2; ++nf)
#pragma unroll
                for (int ks = 0; ks < 2; ++ks)
                    acc[mf][2 + nf] = __builtin_amdgcn_mfma_f32_16x16x32_bf16(aR[mf][ks], b23[nf][ks], acc[mf][2 + nf], 0, 0, 0);
        __builtin_amdgcn_s_setprio(0);
        __builtin_amdgcn_s_barrier();
#pragma unroll
        for (int mf = 0; mf < 4; ++mf)
#pragma unroll
            for (int ks = 0; ks < 2; ++ks)
                aR[mf][ks] = *(const bf16x8*)(aS + 16384 + (mf * 2 + ks) * 1024 + lane_off);
        stageB(0, t + 2, s);
        __builtin_amdgcn_s_setprio(1);
#pragma unroll
        for (int mf = 0; mf < 4; ++mf)
#pragma unroll
            for (int nf = 0; nf < 2; ++nf)
#pragma unroll
                for (int ks = 0; ks < 2; ++ks)
                    acc[4 + mf][2 + nf] = __builtin_amdgcn_mfma_f32_16x16x32_bf16(aR[mf][ks], b23[nf][ks], acc[4 + mf][2 + nf], 0, 0, 0);
        __builtin_amdgcn_s_setprio(0);
        __builtin_amdgcn_s_barrier();
        stageB(1, t + 2, s);
        asm volatile("s_waitcnt vmcnt(6)" ::: "memory");
        __builtin_amdgcn_s_setprio(1);
#pragma unroll
        for (int mf = 0; mf < 4; ++mf)
#pragma unroll
            for (int nf = 0; nf < 2; ++nf)
#pragma unroll
                for (int ks = 0; ks < 2; ++ks)
                    acc[4 + mf][nf] = __builtin_amdgcn_mfma_f32_16x16x32_bf16(aR[mf][ks], b01[nf][ks], acc[4 + mf][nf], 0, 0, 0);
        __builtin_amdgcn_s_setprio(0);
        __builtin_amdgcn_s_barrier();
    }

#pragma unroll
    for (int mq = 0; mq < 2; ++mq)
#pragma unroll
        for (int mf = 0; mf < 4; ++mf) {
            const long rbase = tm + wr * 128 + mq * 64 + mf * 16 + (lane >> 4) * 4;
#pragma unroll
            for (int np = 0; np < 2; ++np)
#pragma unroll
                for (int nf = 0; nf < 2; ++nf) {
                    const long cg = tn + wc * 64 + np * 32 + nf * 16 + rsel;
                    const float bv = __ldg(&bias[cg]);
                    const f32x4 v4 = acc[mq * 4 + mf][np * 2 + nf];
#pragma unroll
                    for (int j = 0; j < 4; ++j) {
                        const float v = v4[j] + bv;
                        const float ge = 0.5f * v * (1.0f + erff(v * 0.70710678118654752f));
                        Cout[(size_t)(rbase + j) * N + cg] = (__bf16)ge;
                    }
                }
        }
}

__global__ __launch_bounds__(512, 2) void gemm2f(
    const bf16_t* __restrict__ A,   // h [M][K]
    const bf16_t* __restrict__ Bm,  // W2 [N][K]
    const float* __restrict__ bias, // b2
    float* __restrict__ outp,       // [M][4][2048]
    const int M, const int N, const int K,
    const float* __restrict__ xg,
    const float* __restrict__ hpost_g,
    const float* __restrict__ Hm_g)
{
    __shared__ __align__(16) char lds[131072];
    const int tid = threadIdx.x;
    const int lane = tid & 63;
    const int w = tid >> 6;
    const int wr = w >> 2;
    const int wc = w & 3;

    long tm, tn;
    tile_swz(blockIdx.x, tm, tn);

    const int NT = K >> 6;

    const int rsel = lane & 15;
    const int ko = (lane >> 4) * 8;
    const int lane_off = rsel * 64 + ((ko ^ (((rsel >> 1) & 3) << 3)) << 1);

    const char* Abytes = (const char*)A;
    const char* Bbytes = (const char*)Bm;
    size_t asrc[2][2], bsrc[2][2];
#pragma unroll
    for (int i = 0; i < 2; ++i) {
        const int d = i * 8192 + tid * 16;
        {
            const int awr = d >> 13, rem = d & 8191;
            const int sub = rem >> 10, rs = sub >> 1, ksub = sub & 1;
            const int rr = (rem >> 6) & 15;
            const int kk = ((rem & 63) >> 1) ^ (((rr >> 1) & 3) << 3);
            const int k = ksub * 32 + kk;
#pragma unroll
            for (int mq = 0; mq < 2; ++mq) {
                const long grow = tm + awr * 128 + mq * 64 + rs * 16 + rr;
                asrc[mq][i] = ((size_t)grow * K + k) * 2;
            }
        }
        {
            const int bwc = d >> 12, rem = d & 4095;
            const int sub = rem >> 10, rs = sub >> 1, ksub = sub & 1;
            const int rr = (rem >> 6) & 15;
            const int kk = ((rem & 63) >> 1) ^ (((rr >> 1) & 3) << 3);
            const int k = ksub * 32 + kk;
#pragma unroll
            for (int np = 0; np < 2; ++np) {
                const long grow = tn + bwc * 64 + np * 32 + rs * 16 + rr;
                bsrc[np][i] = ((size_t)grow * K + k) * 2;
            }
        }
    }

    auto stageA = [&](int mq, int tile, int slot) {
        const int tt = tile < NT ? tile : NT - 1;
        char* dst = lds + slot * 65536 + mq * 16384 + w * 1024;
        gload_lds16(Abytes + asrc[mq][0] + (size_t)tt * 128, dst);
        gload_lds16(Abytes + asrc[mq][1] + (size_t)tt * 128, dst + 8192);
    };
    auto stageB = [&](int np, int tile, int slot) {
        const int tt = tile < NT ? tile : NT - 1;
        char* dst = lds + slot * 65536 + 32768 + np * 16384 + w * 1024;
        gload_lds16(Bbytes + bsrc[np][0] + (size_t)tt * 128, dst);
        gload_lds16(Bbytes + bsrc[np][1] + (size_t)tt * 128, dst + 8192);
    };

    const char* aB = lds + wr * 8192;
    const char* bB = lds + 32768 + wc * 4096;

    f32x4 acc[8][4];
#pragma unroll
    for (int m = 0; m < 8; ++m)
#pragma unroll
        for (int n = 0; n < 4; ++n) acc[m][n] = (f32x4){0.f, 0.f, 0.f, 0.f};

    bf16x8 aR[4][2], b01[2][2], b23[2][2];

    stageA(0, 0, 0); stageB(0, 0, 0); stageB(1, 0, 0); stageA(1, 0, 0);
    stageA(0, 1, 1); stageB(0, 1, 1); stageB(1, 1, 1);
    asm volatile("s_waitcnt vmcnt(6)" ::: "memory");
    __builtin_amdgcn_s_barrier();

    for (int t = 0; t < NT; ++t) {
        const int s = t & 1;
        const char* aS = aB + s * 65536;
        const char* bS = bB + s * 65536;
#pragma unroll
        for (int mf = 0; mf < 4; ++mf)
#pragma unroll
            for (int ks = 0; ks < 2; ++ks)
                aR[mf][ks] = *(const bf16x8*)(aS + (mf * 2 + ks) * 1024 + lane_off);
#pragma unroll
        for (int nf = 0; nf < 2; ++nf)
#pragma unroll
            for (int ks = 0; ks < 2; ++ks)
                b01[nf][ks] = *(const bf16x8*)(bS + (nf * 2 + ks) * 1024 + lane_off);
        stageA(1, t + 1, s ^ 1);
        __builtin_amdgcn_s_setprio(1);
#pragma unroll
        for (int mf = 0; mf < 4; ++mf)
#pragma unroll
            for (int nf = 0; nf < 2; ++nf)
#pragma unroll
                for (int ks = 0; ks < 2; ++ks)
                    acc[mf][nf] = __builtin_amdgcn_mfma_f32_16x16x32_bf16(aR[mf][ks], b01[nf][ks], acc[mf][nf], 0, 0, 0);
        __builtin_amdgcn_s_setprio(0);
        __builtin_amdgcn_s_barrier();
#pragma unroll
        for (int nf = 0; nf < 2; ++nf)
#pragma unroll
            for (int ks = 0; ks < 2; ++ks)
                b23[nf][ks] = *(const bf16x8*)(bS + 16384 + (nf * 2 + ks) * 1024 + lane_off);
        stageA(0, t + 2, s);
        __builtin_amdgcn_s_setprio(1);
#pragma unroll
        for (int mf = 0; mf < 4; ++mf)
#pragma unroll
            for (int nf = 0; nf < 2; ++nf)
#pragma unroll
                for (int ks = 0; ks < 2; ++ks)
                    acc[mf][2 + nf] = __builtin_amdgcn_mfma_f32_16x16x32_bf16(aR[mf][ks], b23[nf][ks], acc[mf][2 + nf], 0, 0, 0);
        __builtin_amdgcn_s_setprio(0);
        __builtin_amdgcn_s_barrier();
#pragma unroll
        for (int mf = 0; mf < 4; ++mf)
#pragma unroll
            for (int ks = 0; ks < 2; ++ks)
                aR[mf][ks] = *(const bf16x8*)(aS + 16384 + (mf * 2 + ks) * 1024 + lane_off);
        stageB(0, t + 2, s);
        __builtin_amdgcn_s_setprio(1);
#pragma unroll
        for (int mf = 0; mf < 4; ++mf)
#pragma unroll
            for (int nf = 0; nf < 2; ++nf)
#pragma unroll
                for (int ks = 0; ks < 2; ++ks)
                    acc[4 + mf][2 + nf] = __builtin_amdgcn_mfma_f32_16x16x32_bf16(aR[mf][ks], b23[nf][ks], acc[4 + mf][2 + nf], 0, 0, 0);
        __builtin_amdgcn_s_setprio(0);
        __builtin_amdgcn_s_barrier();
        stageB(1, t + 2, s);
        asm volatile("s_waitcnt vmcnt(6)" ::: "memory");
        __builtin_amdgcn_s_setprio(1);
#pragma unroll
        for (int mf = 0; mf < 4; ++mf)
#pragma unroll
            for (int nf = 0; nf < 2; ++nf)
#pragma unroll
                for (int ks = 0; ks < 2; ++ks)
                    acc[4 + mf][nf] = __builtin_amdgcn_mfma_f32_16x16x32_bf16(aR[mf][ks], b01[nf][ks], acc[4 + mf][nf], 0, 0, 0);
        __builtin_amdgcn_s_setprio(0);
        __builtin_amdgcn_s_barrier();
    }

    // fused final remix epilogue (plain stores)
#pragma unroll
    for (int mq = 0; mq < 2; ++mq)
#pragma unroll
        for (int mf = 0; mf < 4; ++mf) {
            const long rbase = tm + wr * 128 + mq * 64 + mf * 16 + (lane >> 4) * 4;
#pragma unroll
            for (int j = 0; j < 4; ++j) {
                const long tok = rbase + j;
                float H[16], hq[4];
#pragma unroll
                for (int z = 0; z < 16; ++z) H[z] = __ldg(&Hm_g[tok * 16 + z]);
#pragma unroll
                for (int z = 0; z < 4; ++z) hq[z] = __ldg(&hpost_g[tok * 4 + z]);
                const float* xrow = xg + (size_t)tok * (size_t)NC_DIM;
                float* orow = outp + (size_t)tok * (size_t)NC_DIM;
#pragma unroll
                for (int np = 0; np < 2; ++np)
#pragma unroll
                    for (int nf = 0; nf < 2; ++nf) {
                        const long cg = tn + wc * 64 + np * 32 + nf * 16 + rsel;
                        const float lo = acc[mq * 4 + mf][np * 2 + nf][j] + __ldg(&bias[cg]);
                        const float x0 = xrow[cg];
                        const float x1 = xrow[2048 + cg];
                        const float x2 = xrow[4096 + cg];
                        const float x3 = xrow[6144 + cg];
#pragma unroll
                        for (int i = 0; i < 4; ++i)
                            orow[i * 2048 + cg] =
                                H[i * 4 + 0] * x0 + H[i * 4 + 1] * x1 +
                                H[i * 4 + 2] * x2 + H[i * 4 + 3] * x3 + hq[i] * lo;
                    }
            }
        }
}

extern "C" void kernel_launch(void* const* d_in, const int* in_sizes, int n_in,
                              void* d_out, int out_size, void* d_ws, size_t ws_size,
                              hipStream_t stream) {
    const float* x     = (const float*)d_in[0];
    const float* Wall  = (const float*)d_in[1];
    const float* ball  = (const float*)d_in[2];
    const float* apre  = (const float*)d_in[3];
    const float* apost = (const float*)d_in[4];
    const float* ares  = (const float*)d_in[5];
    const float* W1    = (const float*)d_in[6];
    const float* b1    = (const float*)d_in[7];
    const float* W2    = (const float*)d_in[8];
    const float* b2    = (const float*)d_in[9];
    const float* perm  = (const float*)d_in[10];
    float* out = (float*)d_out;
    char* ws = (char*)d_ws;

    // workspace layout (bytes)
    bf16_t* W1b  = (bf16_t*)(ws);                  //  32 MB  [8192][2048]
    bf16_t* W2b  = (bf16_t*)(ws + 33554432ull);    //  32 MB  [2048][8192]
    bf16_t* li   = (bf16_t*)(ws + 67108864ull);    //  32 MB  [8192][2048]
    bf16_t* h    = (bf16_t*)(ws + 100663296ull);   // 128 MB  [8192][8192]
    float*  hpost= (float*)(ws + 302120960ull);    // 128 KB  [8192][4]
    float*  Hm   = (float*)(ws + 302252032ull);    // 512 KB  [8192][16]

    cvt_both<<<2048, 256, 0, stream>>>(W1, W2, W1b, W2b, 16777216 / 4);
    k_proj<<<256, 256, 0, stream>>>(x, Wall, ball, apre, apost, ares, perm, hpost, Hm, li);
    gemm1k<<<1024, 512, 0, stream>>>(li, W1b, b1, h, 8192, 8192, 2048);
    gemm2f<<<256, 512, 0, stream>>>(h, W2b, b2, out, 8192, 2048, 8192,
                                    x, hpost, Hm);
}

// Round 16
// 782.524 us; speedup vs baseline: 7.6044x; 1.0026x over previous
//
#include <hip/hip_runtime.h>
#include <hip/hip_bf16.h>
#include <math.h>

#define NC_DIM 8192
#define C_DIM 2048
#define NTOK 8192
#define EPS_RMS 1.1920929e-07f

typedef __bf16 bf16_t;
typedef __attribute__((ext_vector_type(8))) __bf16 bf16x8;
typedef __attribute__((ext_vector_type(4))) __bf16 bf16x4;
typedef __attribute__((ext_vector_type(4))) float f32x4;

__device__ __forceinline__ void gload_lds16(const void* g, void* l) {
    __builtin_amdgcn_global_load_lds(
        (const __attribute__((address_space(1))) void*)g,
        (__attribute__((address_space(3))) void*)l, 16, 0, 0);
}

// 2D-chunked XCD swizzle (bijective for grid=1024 and grid=256)
__device__ __forceinline__ void tile_swz(int bid, long& tm, long& tn) {
    const int x8 = bid & 7;
    const int l = bid >> 3;
    tm = (long)(x8 * 4 + ((l >> 3) & 3)) * 256;
    tn = (long)((l >> 5) * 8 + (l & 7)) * 256;
}

// ---------------- k_front: heterogeneous grid -----------------------------
// blocks 0..255   : projection + per-token scalars + fused layer-input mix
// blocks 256..2303: W1/W2 fp32->bf16 conversion (independent of k_proj part;
//                   co-schedules into wave slots k_proj leaves idle)
__global__ __launch_bounds__(256) void k_front(
    const float* __restrict__ x,      // [NTOK][8192]
    const float* __restrict__ Wall,   // [32][8192]
    const float* __restrict__ ball,   // [32]
    const float* __restrict__ apre,
    const float* __restrict__ apost,
    const float* __restrict__ ares,
    const float* __restrict__ perm,   // [24][16]
    float* __restrict__ hpost_g,      // [NTOK][4]
    float* __restrict__ Hm_g,         // [NTOK][16]
    bf16_t* __restrict__ li,          // [NTOK][2048]
    const float* __restrict__ W1,
    const float* __restrict__ W2,
    bf16_t* __restrict__ W1b,
    bf16_t* __restrict__ W2b)
{
    __shared__ __align__(16) bf16_t xs[32 * 264];
    __shared__ __align__(16) bf16_t wsl[32 * 264];
    __shared__ float dparts[4][32][32];
    __shared__ float ssq_s[32];
    __shared__ float Ps[384];
    __shared__ float hps[32][4];

    const int t = threadIdx.x;

    if (blockIdx.x >= 256) {
        // ---- cvt part: grid-stride over 4M float4 per weight matrix ----
        const int bid = blockIdx.x - 256;
        int i = bid * 256 + t;
        const int stride = 2048 * 256;
        for (; i < 4194304; i += stride) {
            f32x4 v = ((const f32x4*)W1)[i];
            bf16x4 bv;
            bv.x = (__bf16)v.x; bv.y = (__bf16)v.y; bv.z = (__bf16)v.z; bv.w = (__bf16)v.w;
            ((bf16x4*)W1b)[i] = bv;
            f32x4 u = ((const f32x4*)W2)[i];
            bf16x4 bu;
            bu.x = (__bf16)u.x; bu.y = (__bf16)u.y; bu.z = (__bf16)u.z; bu.w = (__bf16)u.w;
            ((bf16x4*)W2b)[i] = bu;
        }
        return;
    }

    // ---- k_proj part ----
    const int lane = t & 63;
    const int w = t >> 6;
    const int tok0 = blockIdx.x * 32;

    for (int i = t; i < 384; i += 256) Ps[i] = perm[i];

    const int row = t >> 3;
    const int i8 = t & 7;

    const float* xrow = x + (size_t)(tok0 + row) * (size_t)NC_DIM;
    const float* wrow = Wall + (size_t)row * (size_t)NC_DIM;

    float ssq = 0.0f;
    f32x4 acc[2][2];
#pragma unroll
    for (int m = 0; m < 2; ++m)
#pragma unroll
        for (int n = 0; n < 2; ++n) acc[m][n] = (f32x4){0.f, 0.f, 0.f, 0.f};

    const int rsel = lane & 15;
    const int ko_base = (lane >> 4) * 8;

    for (int kt = 0; kt < NC_DIM; kt += 256) {
        __syncthreads();
#pragma unroll
        for (int q = 0; q < 8; ++q) {
            const int col = (i8 + q * 8) * 4;
            f32x4 v = *(const f32x4*)(xrow + kt + col);
            ssq += v.x * v.x + v.y * v.y + v.z * v.z + v.w * v.w;
            bf16x4 bv;
            bv.x = (__bf16)v.x; bv.y = (__bf16)v.y; bv.z = (__bf16)v.z; bv.w = (__bf16)v.w;
            *(bf16x4*)(xs + row * 264 + col) = bv;
            f32x4 u = *(const f32x4*)(wrow + kt + col);
            bf16x4 bu;
            bu.x = (__bf16)u.x; bu.y = (__bf16)u.y; bu.z = (__bf16)u.z; bu.w = (__bf16)u.w;
            *(bf16x4*)(wsl + row * 264 + col) = bu;
        }
        __syncthreads();
#pragma unroll
        for (int ks = 0; ks < 2; ++ks) {
            const int ko = w * 64 + ks * 32 + ko_base;
            bf16x8 a0 = *(const bf16x8*)(xs + rsel * 264 + ko);
            bf16x8 a1 = *(const bf16x8*)(xs + (16 + rsel) * 264 + ko);
            bf16x8 b0 = *(const bf16x8*)(wsl + rsel * 264 + ko);
            bf16x8 b1 = *(const bf16x8*)(wsl + (16 + rsel) * 264 + ko);
            acc[0][0] = __builtin_amdgcn_mfma_f32_16x16x32_bf16(a0, b0, acc[0][0], 0, 0, 0);
            acc[0][1] = __builtin_amdgcn_mfma_f32_16x16x32_bf16(a0, b1, acc[0][1], 0, 0, 0);
            acc[1][0] = __builtin_amdgcn_mfma_f32_16x16x32_bf16(a1, b0, acc[1][0], 0, 0, 0);
            acc[1][1] = __builtin_amdgcn_mfma_f32_16x16x32_bf16(a1, b1, acc[1][1], 0, 0, 0);
        }
    }

    ssq += __shfl_xor(ssq, 1);
    ssq += __shfl_xor(ssq, 2);
    ssq += __shfl_xor(ssq, 4);
    if (i8 == 0) ssq_s[row] = ssq;

    const int cr = (lane >> 4) * 4;
#pragma unroll
    for (int m = 0; m < 2; ++m)
#pragma unroll
        for (int n = 0; n < 2; ++n)
#pragma unroll
            for (int j = 0; j < 4; ++j)
                dparts[w][m * 16 + cr + j][n * 16 + rsel] = acc[m][n][j];
    __syncthreads();

    if (t < 32) {
        const int g = tok0 + t;
        const float rinv = rsqrtf(ssq_s[t] * (1.0f / (float)NC_DIM) + EPS_RMS);
        float proj[32];
#pragma unroll
        for (int r = 0; r < 32; ++r)
            proj[r] = (dparts[0][t][r] + dparts[1][t][r] + dparts[2][t][r] + dparts[3][t][r]) * rinv;
        const float aP = apre[0], aQ = apost[0], aR = ares[0];
        float hp[4], hq[4];
#pragma unroll
        for (int i = 0; i < 4; ++i) {
            hp[i] = 1.0f / (1.0f + expf(-(aP * proj[i] + __ldg(&ball[i]))));
            hq[i] = 2.0f / (1.0f + expf(-(aQ * proj[4 + i] + __ldg(&ball[4 + i]))));
            hps[t][i] = hp[i];
        }
        float zb[24];
        float mx = -1e30f;
#pragma unroll
        for (int p = 0; p < 24; ++p) {
            zb[p] = aR * proj[8 + p] + __ldg(&ball[8 + p]);
            mx = fmaxf(mx, zb[p]);
        }
        float s = 0.f;
#pragma unroll
        for (int p = 0; p < 24; ++p) { zb[p] = expf(zb[p] - mx); s += zb[p]; }
        const float is = 1.0f / s;
        float Hr[16];
#pragma unroll
        for (int idx = 0; idx < 16; ++idx) Hr[idx] = 0.f;
#pragma unroll
        for (int p = 0; p < 24; ++p) {
            const float a = zb[p] * is;
#pragma unroll
            for (int idx = 0; idx < 16; ++idx) Hr[idx] += a * Ps[p * 16 + idx];
        }
#pragma unroll
        for (int i = 0; i < 4; ++i) {
            hpost_g[(size_t)g * 4 + i] = hq[i];
#pragma unroll
            for (int j = 0; j < 4; ++j)
                Hm_g[(size_t)g * 16 + i * 4 + j] = Hr[i * 4 + j] - hq[i] * hp[j];
        }
    }
    __syncthreads();

    // ---- fused k_mix ----
    const float h0 = hps[row][0], h1 = hps[row][1], h2 = hps[row][2], h3 = hps[row][3];
    bf16_t* lo = li + (size_t)(tok0 + row) * (size_t)C_DIM;
#pragma unroll 4
    for (int q = 0; q < 64; ++q) {
        const int c = (i8 + q * 8) * 4;
        f32x4 v0 = *(const f32x4*)(xrow + c);
        f32x4 v1 = *(const f32x4*)(xrow + 2048 + c);
        f32x4 v2 = *(const f32x4*)(xrow + 4096 + c);
        f32x4 v3 = *(const f32x4*)(xrow + 6144 + c);
        f32x4 r = h0 * v0 + h1 * v1 + h2 * v2 + h3 * v3;
        bf16x4 bv;
        bv.x = (__bf16)r.x; bv.y = (__bf16)r.y; bv.z = (__bf16)r.z; bv.w = (__bf16)r.w;
        *(bf16x4*)(lo + c) = bv;
    }
}

// ---------------- GEMM core (R4/R12 best: 256^2, BK=64, 1 barrier/phase,
// counted vmcnt(6), conflict-free swizzle, 2D-chunked XCD swizzle) ---------

__global__ __launch_bounds__(512, 2) void gemm1k(
    const bf16_t* __restrict__ A,   // li [M][K]
    const bf16_t* __restrict__ Bm,  // W1 [N][K]
    const float* __restrict__ bias, // b1
    bf16_t* __restrict__ Cout,      // h [M][N]
    const int M, const int N, const int K)
{
    __shared__ __align__(16) char lds[131072];
    const int tid = threadIdx.x;
    const int lane = tid & 63;
    const int w = tid >> 6;
    const int wr = w >> 2;
    const int wc = w & 3;

    long tm, tn;
    tile_swz(blockIdx.x, tm, tn);

    const int NT = K >> 6;

    const int rsel = lane & 15;
    const int ko = (lane >> 4) * 8;
    const int lane_off = rsel * 64 + ((ko ^ (((rsel >> 1) & 3) << 3)) << 1);

    const char* Abytes = (const char*)A;
    const char* Bbytes = (const char*)Bm;
    size_t asrc[2][2], bsrc[2][2];
#pragma unroll
    for (int i = 0; i < 2; ++i) {
        const int d = i * 8192 + tid * 16;
        {
            const int awr = d >> 13, rem = d & 8191;
            const int sub = rem >> 10, rs = sub >> 1, ksub = sub & 1;
            const int rr = (rem >> 6) & 15;
            const int kk = ((rem & 63) >> 1) ^ (((rr >> 1) & 3) << 3);
            const int k = ksub * 32 + kk;
#pragma unroll
            for (int mq = 0; mq < 2; ++mq) {
                const long grow = tm + awr * 128 + mq * 64 + rs * 16 + rr;
                asrc[mq][i] = ((size_t)grow * K + k) * 2;
            }
        }
        {
            const int bwc = d >> 12, rem = d & 4095;
            const int sub = rem >> 10, rs = sub >> 1, ksub = sub & 1;
            const int rr = (rem >> 6) & 15;
            const int kk = ((rem & 63) >> 1) ^ (((rr >> 1) & 3) << 3);
            const int k = ksub * 32 + kk;
#pragma unroll
            for (int np = 0; np < 2; ++np) {
                const long grow = tn + bwc * 64 + np * 32 + rs * 16 + rr;
                bsrc[np][i] = ((size_t)grow * K + k) * 2;
            }
        }
    }

    auto stageA = [&](int mq, int tile, int slot) {
        const int tt = tile < NT ? tile : NT - 1;
        char* dst = lds + slot * 65536 + mq * 16384 + w * 1024;
        gload_lds16(Abytes + asrc[mq][0] + (size_t)tt * 128, dst);
        gload_lds16(Abytes + asrc[mq][1] + (size_t)tt * 128, dst + 8192);
    };
    auto stageB = [&](int np, int tile, int slot) {
        const int tt = tile < NT ? tile : NT - 1;
        char* dst = lds + slot * 65536 + 32768 + np * 16384 + w * 1024;
        gload_lds16(Bbytes + bsrc[np][0] + (size_t)tt * 128, dst);
        gload_lds16(Bbytes + bsrc[np][1] + (size_t)tt * 128, dst + 8192);
    };

    const char* aB = lds + wr * 8192;
    const char* bB = lds + 32768 + wc * 4096;

    f32x4 acc[8][4];
#pragma unroll
    for (int m = 0; m < 8; ++m)
#pragma unroll
        for (int n = 0; n < 4; ++n) acc[m][n] = (f32x4){0.f, 0.f, 0.f, 0.f};

    bf16x8 aR[4][2], b01[2][2], b23[2][2];

    stageA(0, 0, 0); stageB(0, 0, 0); stageB(1, 0, 0); stageA(1, 0, 0);
    stageA(0, 1, 1); stageB(0, 1, 1); stageB(1, 1, 1);
    asm volatile("s_waitcnt vmcnt(6)" ::: "memory");
    __builtin_amdgcn_s_barrier();

    for (int t = 0; t < NT; ++t) {
        const int s = t & 1;
        const char* aS = aB + s * 65536;
        const char* bS = bB + s * 65536;
#pragma unroll
        for (int mf = 0; mf < 4; ++mf)
#pragma unroll
            for (int ks = 0; ks < 2; ++ks)
                aR[mf][ks] = *(const bf16x8*)(aS + (mf * 2 + ks) * 1024 + lane_off);
#pragma unroll
        for (int nf = 0; nf < 2; ++nf)
#pragma unroll
            for (int ks = 0; ks < 2; ++ks)
                b01[nf][ks] = *(const bf16x8*)(bS + (nf * 2 + ks) * 1024 + lane_off);
        stageA(1, t + 1, s ^ 1);
        __builtin_amdgcn_s_setprio(1);
#pragma unroll
        for (int mf = 0; mf < 4; ++mf)
#pragma unroll
            for (int nf = 0; nf < 2; ++nf)
#pragma unroll
                for (int ks = 0; ks < 2; ++ks)
                    acc[mf][nf] = __builtin_amdgcn_mfma_f32_16x16x32_bf16(aR[mf][ks], b01[nf][ks], acc[mf][nf], 0, 0, 0);
        __builtin_amdgcn_s_setprio(0);
        __builtin_amdgcn_s_barrier();
#pragma unroll
        for (int nf = 0; nf < 2; ++nf)
#pragma unroll
            for (int ks = 0; ks < 2; ++ks)
                b23[nf][ks] = *(const bf16x8*)(bS + 16384 + (nf * 2 + ks) * 1024 + lane_off);
        stageA(0, t + 2, s);
        __builtin_amdgcn_s_setprio(1);
#pragma unroll
        for (int mf = 0; mf < 4; ++mf)
#pragma unroll
            for (int nf = 0; nf < 2; ++nf)
#pragma unroll
                for (int ks = 0; ks < 2; ++ks)
                    acc[mf][2 + nf] = __builtin_amdgcn_mfma_f32_16x16x32_bf16(aR[mf][ks], b23[nf][ks], acc[mf][2 + nf], 0, 0, 0);
        __builtin_amdgcn_s_setprio(0);
        __builtin_amdgcn_s_barrier();
#pragma unroll
        for (int mf = 0; mf < 4; ++mf)
#pragma unroll
            for (int ks = 0; ks < 2; ++ks)
                aR[mf][ks] = *(const bf16x8*)(aS + 16384 + (mf * 2 + ks) * 1024 + lane_off);
        stageB(0, t + 2, s);
        __builtin_amdgcn_s_setprio(1);
#pragma unroll
        for (int mf = 0; mf < 4; ++mf)
#pragma unroll
            for (int nf = 0; nf < 2; ++nf)
#pragma unroll
                for (int ks = 0; ks < 2; ++ks)
                    acc[4 + mf][2 + nf] = __builtin_amdgcn_mfma_f32_16x16x32_bf16(aR[mf][ks], b23[nf][ks], acc[4 + mf][2 + nf], 0, 0, 0);
        __builtin_amdgcn_s_setprio(0);
        __builtin_amdgcn_s_barrier();
        stageB(1, t + 2, s);
        asm volatile("s_waitcnt vmcnt(6)" ::: "memory");
        __builtin_amdgcn_s_setprio(1);
#pragma unroll
        for (int mf = 0; mf < 4; ++mf)
#pragma unroll
            for (int nf = 0; nf < 2; ++nf)
#pragma unroll
                for (int ks = 0; ks < 2; ++ks)
                    acc[4 + mf][nf] = __builtin_amdgcn_mfma_f32_16x16x32_bf16(aR[mf][ks], b01[nf][ks], acc[4 + mf][nf], 0, 0, 0);
        __builtin_amdgcn_s_setprio(0);
        __builtin_amdgcn_s_barrier();
    }

#pragma unroll
    for (int mq = 0; mq < 2; ++mq)
#pragma unroll
        for (int mf = 0; mf < 4; ++mf) {
            const long rbase = tm + wr * 128 + mq * 64 + mf * 16 + (lane >> 4) * 4;
#pragma unroll
            for (int np = 0; np < 2; ++np)
#pragma unroll
                for (int nf = 0; nf < 2; ++nf) {
                    const long cg = tn + wc * 64 + np * 32 + nf * 16 + rsel;
                    const float bv = __ldg(&bias[cg]);
                    const f32x4 v4 = acc[mq * 4 + mf][np * 2 + nf];
#pragma unroll
                    for (int j = 0; j < 4; ++j) {
                        const float v = v4[j] + bv;
                        const float ge = 0.5f * v * (1.0f + erff(v * 0.70710678118654752f));
                        Cout[(size_t)(rbase + j) * N + cg] = (__bf16)ge;
                    }
                }
        }
}

__global__ __launch_bounds__(512, 2) void gemm2f(
    const bf16_t* __restrict__ A,   // h [M][K]
    const bf16_t* __restrict__ Bm,  // W2 [N][K]
    const float* __restrict__ bias, // b2
    float* __restrict__ outp,       // [M][4][2048]
    const int M, const int N, const int K,
    const float* __restrict__ xg,
    const float* __restrict__ hpost_g,
    const float* __restrict__ Hm_g)
{
    __shared__ __align__(16) char lds[131072];
    const int tid = threadIdx.x;
    const int lane = tid & 63;
    const int w = tid >> 6;
    const int wr = w >> 2;
    const int wc = w & 3;

    long tm, tn;
    tile_swz(blockIdx.x, tm, tn);

    const int NT = K >> 6;

    const int rsel = lane & 15;
    const int ko = (lane >> 4) * 8;
    const int lane_off = rsel * 64 + ((ko ^ (((rsel >> 1) & 3) << 3)) << 1);

    const char* Abytes = (const char*)A;
    const char* Bbytes = (const char*)Bm;
    size_t asrc[2][2], bsrc[2][2];
#pragma unroll
    for (int i = 0; i < 2; ++i) {
        const int d = i * 8192 + tid * 16;
        {
            const int awr = d >> 13, rem = d & 8191;
            const int sub = rem >> 10, rs = sub >> 1, ksub = sub & 1;
            const int rr = (rem >> 6) & 15;
            const int kk = ((rem & 63) >> 1) ^ (((rr >> 1) & 3) << 3);
            const int k = ksub * 32 + kk;
#pragma unroll
            for (int mq = 0; mq < 2; ++mq) {
                const long grow = tm + awr * 128 + mq * 64 + rs * 16 + rr;
                asrc[mq][i] = ((size_t)grow * K + k) * 2;
            }
        }
        {
            const int bwc = d >> 12, rem = d & 4095;
            const int sub = rem >> 10, rs = sub >> 1, ksub = sub & 1;
            const int rr = (rem >> 6) & 15;
            const int kk = ((rem & 63) >> 1) ^ (((rr >> 1) & 3) << 3);
            const int k = ksub * 32 + kk;
#pragma unroll
            for (int np = 0; np < 2; ++np) {
                const long grow = tn + bwc * 64 + np * 32 + rs * 16 + rr;
                bsrc[np][i] = ((size_t)grow * K + k) * 2;
            }
        }
    }

    auto stageA = [&](int mq, int tile, int slot) {
        const int tt = tile < NT ? tile : NT - 1;
        char* dst = lds + slot * 65536 + mq * 16384 + w * 1024;
        gload_lds16(Abytes + asrc[mq][0] + (size_t)tt * 128, dst);
        gload_lds16(Abytes + asrc[mq][1] + (size_t)tt * 128, dst + 8192);
    };
    auto stageB = [&](int np, int tile, int slot) {
        const int tt = tile < NT ? tile : NT - 1;
        char* dst = lds + slot * 65536 + 32768 + np * 16384 + w * 1024;
        gload_lds16(Bbytes + bsrc[np][0] + (size_t)tt * 128, dst);
        gload_lds16(Bbytes + bsrc[np][1] + (size_t)tt * 128, dst + 8192);
    };

    const char* aB = lds + wr * 8192;
    const char* bB = lds + 32768 + wc * 4096;

    f32x4 acc[8][4];
#pragma unroll
    for (int m = 0; m < 8; ++m)
#pragma unroll
        for (int n = 0; n < 4; ++n) acc[m][n] = (f32x4){0.f, 0.f, 0.f, 0.f};

    bf16x8 aR[4][2], b01[2][2], b23[2][2];

    stageA(0, 0, 0); stageB(0, 0, 0); stageB(1, 0, 0); stageA(1, 0, 0);
    stageA(0, 1, 1); stageB(0, 1, 1); stageB(1, 1, 1);
    asm volatile("s_waitcnt vmcnt(6)" ::: "memory");
    __builtin_amdgcn_s_barrier();

    for (int t = 0; t < NT; ++t) {
        const int s = t & 1;
        const char* aS = aB + s * 65536;
        const char* bS = bB + s * 65536;
#pragma unroll
        for (int mf = 0; mf < 4; ++mf)
#pragma unroll
            for (int ks = 0; ks < 2; ++ks)
                aR[mf][ks] = *(const bf16x8*)(aS + (mf * 2 + ks) * 1024 + lane_off);
#pragma unroll
        for (int nf = 0; nf < 2; ++nf)
#pragma unroll
            for (int ks = 0; ks < 2; ++ks)
                b01[nf][ks] = *(const bf16x8*)(bS + (nf * 2 + ks) * 1024 + lane_off);
        stageA(1, t + 1, s ^ 1);
        __builtin_amdgcn_s_setprio(1);
#pragma unroll
        for (int mf = 0; mf < 4; ++mf)
#pragma unroll
            for (int nf = 0; nf < 2; ++nf)
#pragma unroll
                for (int ks = 0; ks < 2; ++ks)
                    acc[mf][nf] = __builtin_amdgcn_mfma_f32_16x16x32_bf16(aR[mf][ks], b01[nf][ks], acc[mf][nf], 0, 0, 0);
        __builtin_amdgcn_s_setprio(0);
        __builtin_amdgcn_s_barrier();
#pragma unroll
        for (int nf = 0; nf < 2; ++nf)
#pragma unroll
            for (int ks = 0; ks < 2; ++ks)
                b23[nf][ks] = *(const bf16x8*)(bS + 16384 + (nf * 2 + ks) * 1024 + lane_off);
        stageA(0, t + 2, s);
        __builtin_amdgcn_s_setprio(1);
#pragma unroll
        for (int mf = 0; mf < 4; ++mf)
#pragma unroll
            for (int nf = 0; nf < 2; ++nf)
#pragma unroll
                for (int ks = 0; ks < 2; ++ks)
                    acc[mf][2 + nf] = __builtin_amdgcn_mfma_f32_16x16x32_bf16(aR[mf][ks], b23[nf][ks], acc[mf][2 + nf], 0, 0, 0);
        __builtin_amdgcn_s_setprio(0);
        __builtin_amdgcn_s_barrier();
#pragma unroll
        for (int mf = 0; mf < 4; ++mf)
#pragma unroll
            for (int ks = 0; ks < 2; ++ks)
                aR[mf][ks] = *(const bf16x8*)(aS + 16384 + (mf * 2 + ks) * 1024 + lane_off);
        stageB(0, t + 2, s);
        __builtin_amdgcn_s_setprio(1);
#pragma unroll
        for (int mf = 0; mf < 4; ++mf)
#pragma unroll
            for (int nf = 0; nf < 2; ++nf)
#pragma unroll
                for (int ks = 0; ks < 2; ++ks)
                    acc[4 + mf][2 + nf] = __builtin_amdgcn_mfma_f32_16x16x32_bf16(aR[mf][ks], b23[nf][ks], acc[4 + mf][2 + nf], 0, 0, 0);
        __builtin_amdgcn_s_setprio(0);
        __builtin_amdgcn_s_barrier();
        stageB(1, t + 2, s);
        asm volatile("s_waitcnt vmcnt(6)" ::: "memory");
        __builtin_amdgcn_s_setprio(1);
#pragma unroll
        for (int mf = 0; mf < 4; ++mf)
#pragma unroll
            for (int nf = 0; nf < 2; ++nf)
#pragma unroll
                for (int ks = 0; ks < 2; ++ks)
                    acc[4 + mf][nf] = __builtin_amdgcn_mfma_f32_16x16x32_bf16(aR[mf][ks], b01[nf][ks], acc[4 + mf][nf], 0, 0, 0);
        __builtin_amdgcn_s_setprio(0);
        __builtin_amdgcn_s_barrier();
    }

    // fused final remix epilogue (plain stores)
#pragma unroll
    for (int mq = 0; mq < 2; ++mq)
#pragma unroll
        for (int mf = 0; mf < 4; ++mf) {
            const long rbase = tm + wr * 128 + mq * 64 + mf * 16 + (lane >> 4) * 4;
#pragma unroll
            for (int j = 0; j < 4; ++j) {
                const long tok = rbase + j;
                float H[16], hq[4];
#pragma unroll
                for (int z = 0; z < 16; ++z) H[z] = __ldg(&Hm_g[tok * 16 + z]);
#pragma unroll
                for (int z = 0; z < 4; ++z) hq[z] = __ldg(&hpost_g[tok * 4 + z]);
                const float* xrow = xg + (size_t)tok * (size_t)NC_DIM;
                float* orow = outp + (size_t)tok * (size_t)NC_DIM;
#pragma unroll
                for (int np = 0; np < 2; ++np)
#pragma unroll
                    for (int nf = 0; nf < 2; ++nf) {
                        const long cg = tn + wc * 64 + np * 32 + nf * 16 + rsel;
                        const float lo = acc[mq * 4 + mf][np * 2 + nf][j] + __ldg(&bias[cg]);
                        const float x0 = xrow[cg];
                        const float x1 = xrow[2048 + cg];
                        const float x2 = xrow[4096 + cg];
                        const float x3 = xrow[6144 + cg];
#pragma unroll
                        for (int i = 0; i < 4; ++i)
                            orow[i * 2048 + cg] =
                                H[i * 4 + 0] * x0 + H[i * 4 + 1] * x1 +
                                H[i * 4 + 2] * x2 + H[i * 4 + 3] * x3 + hq[i] * lo;
                    }
            }
        }
}

extern "C" void kernel_launch(void* const* d_in, const int* in_sizes, int n_in,
                              void* d_out, int out_size, void* d_ws, size_t ws_size,
                              hipStream_t stream) {
    const float* x     = (const float*)d_in[0];
    const float* Wall  = (const float*)d_in[1];
    const float* ball  = (const float*)d_in[2];
    const float* apre  = (const float*)d_in[3];
    const float* apost = (const float*)d_in[4];
    const float* ares  = (const float*)d_in[5];
    const float* W1    = (const float*)d_in[6];
    const float* b1    = (const float*)d_in[7];
    const float* W2    = (const float*)d_in[8];
    const float* b2    = (const float*)d_in[9];
    const float* perm  = (const float*)d_in[10];
    float* out = (float*)d_out;
    char* ws = (char*)d_ws;

    // workspace layout (bytes)
    bf16_t* W1b  = (bf16_t*)(ws);                  //  32 MB  [8192][2048]
    bf16_t* W2b  = (bf16_t*)(ws + 33554432ull);    //  32 MB  [2048][8192]
    bf16_t* li   = (bf16_t*)(ws + 67108864ull);    //  32 MB  [8192][2048]
    bf16_t* h    = (bf16_t*)(ws + 100663296ull);   // 128 MB  [8192][8192]
    float*  hpost= (float*)(ws + 302120960ull);    // 128 KB  [8192][4]
    float*  Hm   = (float*)(ws + 302252032ull);    // 512 KB  [8192][16]

    k_front<<<2304, 256, 0, stream>>>(x, Wall, ball, apre, apost, ares, perm,
                                      hpost, Hm, li, W1, W2, W1b, W2b);
    gemm1k<<<1024, 512, 0, stream>>>(li, W1b, b1, h, 8192, 8192, 2048);
    gemm2f<<<256, 512, 0, stream>>>(h, W2b, b2, out, 8192, 2048, 8192,
                                    x, hpost, Hm);
}